// Round 13
// baseline (110.587 us; speedup 1.0000x reference)
//
#include <hip/hip_runtime.h>
#include <hip/hip_bf16.h>
#include <stdint.h>

typedef unsigned short u16;
typedef unsigned int u32;
typedef __bf16 bf16x8 __attribute__((ext_vector_type(8)));
typedef float f32x4 __attribute__((ext_vector_type(4)));
typedef float f32x16 __attribute__((ext_vector_type(16)));
typedef u32 u32x4 __attribute__((ext_vector_type(4)));

#define B_   2
#define S_   2048
#define D_   1024
#define H_   16
#define HD_  64

__device__ __forceinline__ u16 f2bf(float f) {
    u32 u = __float_as_uint(f);
    u32 r = (u + 0x7FFFu + ((u >> 16) & 1u)) >> 16;   // RNE; inputs never NaN/Inf
    return (u16)r;
}
__device__ __forceinline__ float bf2f(u16 s) { return __uint_as_float(((u32)s) << 16); }

__device__ __forceinline__ f32x4 mfma16(bf16x8 a, bf16x8 b, f32x4 c) {
    return __builtin_amdgcn_mfma_f32_16x16x32_bf16(a, b, c, 0, 0, 0);
}
__device__ __forceinline__ f32x16 mfma32(bf16x8 a, bf16x8 b, f32x16 c) {
    return __builtin_amdgcn_mfma_f32_32x32x16_bf16(a, b, c, 0, 0, 0);
}

// async global->LDS, 16B per lane; lds dest must be wave-uniform base (+lane*16)
__device__ __forceinline__ void gl16(const u16* g, u16* l) {
    __builtin_amdgcn_global_load_lds(
        (const __attribute__((address_space(1))) void*)g,
        (__attribute__((address_space(3))) void*)l, 16, 0, 0);
}

// ---------------------------------------------------------------------------
// Fused prep: blocks 0..4095 convert x fp32->bf16 (float4/thread);
// blocks 4096..8191 transpose+convert the 4 weights (z = q/k/v/o).
// ---------------------------------------------------------------------------
__global__ void prep_kernel(const float* __restrict__ x,
                            const float* __restrict__ qw, const float* __restrict__ kw,
                            const float* __restrict__ vw, const float* __restrict__ ow,
                            u16* __restrict__ xbf, u16* __restrict__ wt_all) {
    __shared__ float tile[32][33];
    const int bid = blockIdx.x;
    const int t = threadIdx.x;
    if (bid < 4096) {
        int i = bid * 256 + t;
        float4 v = reinterpret_cast<const float4*>(x)[i];
        uint2 hp;
        hp.x = (u32)f2bf(v.x) | ((u32)f2bf(v.y) << 16);
        hp.y = (u32)f2bf(v.z) | ((u32)f2bf(v.w) << 16);
        reinterpret_cast<uint2*>(xbf)[i] = hp;
        return;
    }
    const int f = bid - 4096;
    const int z = f >> 10;           // weight select
    const int bi = (f & 1023) >> 5;  // input-dim block
    const int bj = f & 31;           // output-dim block
    const float* w = (z == 0) ? qw : (z == 1) ? kw : (z == 2) ? vw : ow;
    u16* thi = wt_all + (size_t)z * 1048576;
    const int tx = t & 31, ty = t >> 5;  // 32 x 8
#pragma unroll
    for (int k = 0; k < 4; k++) {
        int r = ty + k * 8;
        tile[r][tx] = w[(size_t)(bi * 32 + r) * D_ + bj * 32 + tx];
    }
    __syncthreads();
#pragma unroll
    for (int k = 0; k < 4; k++) {
        int r = ty + k * 8;
        thi[(size_t)(bj * 32 + r) * D_ + bi * 32 + tx] = f2bf(tile[tx][r]);
    }
}

// ---------------------------------------------------------------------------
// Fused QKV projection GEMM, plain bf16, LIF epilogue. T4 pipeline:
// 3 LDS buffers, per k-step: counted vmcnt(4) -> raw s_barrier (no drain)
// -> STAGE(k+2) -> compute(k). Tile 128x128, BK=32, 48KB LDS -> 3 blocks/CU.
// proj 0/1 (q/k) -> [bh][s][d]; proj 2 (v) -> [bh][d][s], 8B packed stores.
// ---------------------------------------------------------------------------
__global__ __launch_bounds__(256, 3)
void qkv_gemm(const u16* __restrict__ Ag, const u16* __restrict__ Bg,
              const float* __restrict__ qb, const float* __restrict__ kb,
              const float* __restrict__ vb,
              u16* __restrict__ o0, u16* __restrict__ o1, u16* __restrict__ o2) {
    __shared__ __align__(16) u16 lA[3][128 * 32];  // 24 KB
    __shared__ __align__(16) u16 lB[3][128 * 32];  // 24 KB

    const int t = threadIdx.x;
    const int flat = blockIdx.y * 24 + blockIdx.x;
    const int swz = (flat & 7) * 96 + (flat >> 3);   // bijective, 8 XCD chunks
    const int m0 = (swz / 24) * 128;
    const int n0 = (swz % 24) * 128;
    const int wid = t >> 6, lane = t & 63;
    const int wm = wid >> 1, wn = wid & 1;
    const int lr = lane & 15, lg = lane >> 4;

    f32x4 acc[4][4] = {};

    auto STAGE = [&](int buf, int kk) {  // 4 gl16 per thread
        const int k0 = kk * 32;
#pragma unroll
        for (int p = 0; p < 2; p++) {
            int idx = p * 256 + wid * 64 + lane;
            int row = idx >> 2, sl = idx & 3;
            int slx = sl ^ ((row >> 1) & 3);
            gl16(Ag + (size_t)(m0 + row) * D_ + k0 + slx * 8,
                 &lA[buf][(p * 256 + wid * 64) * 8]);
            gl16(Bg + (size_t)(n0 + row) * D_ + k0 + slx * 8,
                 &lB[buf][(p * 256 + wid * 64) * 8]);
        }
    };

    STAGE(0, 0);
    STAGE(1, 1);

    for (int kk = 0; kk < 32; ++kk) {
        if (kk < 31) asm volatile("s_waitcnt vmcnt(4)" ::: "memory");
        else         asm volatile("s_waitcnt vmcnt(0)" ::: "memory");
        __builtin_amdgcn_s_barrier();
        if (kk < 30) STAGE((kk + 2) % 3, kk + 2);  // lands over next 2 k-steps

        const int cur = kk % 3;
        bf16x8 af[4], bf[4];
#pragma unroll
        for (int m = 0; m < 4; m++) {
            int row = wm * 64 + m * 16 + lr;
            af[m] = *reinterpret_cast<const bf16x8*>(
                &lA[cur][row * 32 + (lg ^ ((row >> 1) & 3)) * 8]);
        }
#pragma unroll
        for (int n = 0; n < 4; n++) {
            int row = wn * 64 + n * 16 + lr;
            bf[n] = *reinterpret_cast<const bf16x8*>(
                &lB[cur][row * 32 + (lg ^ ((row >> 1) & 3)) * 8]);
        }
#pragma unroll
        for (int m = 0; m < 4; m++)
#pragma unroll
            for (int n = 0; n < 4; n++)
                acc[m][n] = mfma16(af[m], bf[n], acc[m][n]);
    }

    // ---- epilogue: bias + LIF + scatter ----
    const int col0f = n0 + wn * 64;
    const int proj = col0f >> 10;  // whole wave-tile shares one proj (64 | 1024)
    const float* bp = (proj == 0) ? qb : (proj == 1) ? kb : vb;
    u16* dst = (proj == 0) ? o0 : (proj == 1) ? o1 : o2;
#pragma unroll
    for (int m = 0; m < 4; m++) {
#pragma unroll
        for (int n = 0; n < 4; n++) {
            u16 agg4[4];
#pragma unroll
            for (int r = 0; r < 4; r++) {
                int row = m0 + wm * 64 + m * 16 + lg * 4 + r;
                int colp = (col0f + n * 16 + lr) & 1023;
                float cur_i = acc[m][n][r] + bp[colp];
                // LIF: 4 steps, subtract reset (detached), spike after update
                float mem = 0.f;
                int cnt = 0;
#pragma unroll
                for (int tt = 0; tt < 4; tt++) {
                    float reset = (mem > 1.f) ? 1.f : 0.f;
                    mem = 0.95f * mem;
                    mem = mem + cur_i;
                    mem = mem - reset;
                    cnt += (mem > 1.f) ? 1 : 0;
                }
                // cnt*0.25 is exactly representable in bf16: truncate, no RNE
                u16 agg = (u16)(__float_as_uint((float)cnt * 0.25f) >> 16);
                if (proj != 2) {
                    int b = row >> 11, s = row & 2047;
                    int h = colp >> 6, d = colp & 63;
                    dst[((size_t)(b * H_ + h) * S_ + s) * HD_ + d] = agg;
                } else {
                    agg4[r] = agg;
                }
            }
            if (proj == 2) {
                // [bh][d][s]: 4 consecutive s per thread -> one 8B store
                int row0 = m0 + wm * 64 + m * 16 + lg * 4;
                int colp = (col0f + n * 16 + lr) & 1023;
                int b = row0 >> 11, s = row0 & 2047;
                int h = colp >> 6, d = colp & 63;
                uint2 pk;
                pk.x = (u32)agg4[0] | ((u32)agg4[1] << 16);
                pk.y = (u32)agg4[2] | ((u32)agg4[3] << 16);
                *reinterpret_cast<uint2*>(
                    &dst[((size_t)(b * H_ + h) * HD_ + d) * S_ + s]) = pk;
            }
        }
    }
}

// ---------------------------------------------------------------------------
// Output projection, plain bf16, T4 pipeline (3 buffers, counted vmcnt(2)).
// C = a @ W^T + bias, fp32 out. Tile 64x64, BK=32. 24KB LDS -> 4 blocks/CU.
// ---------------------------------------------------------------------------
__global__ __launch_bounds__(256, 4)
void o_gemm(const u16* __restrict__ Ag, const u16* __restrict__ Bhg,
            const float* __restrict__ bias, float* __restrict__ out) {
    __shared__ __align__(16) u16 lA[3][64 * 32];    // 12 KB
    __shared__ __align__(16) u16 lB[3][64 * 32];    // 12 KB

    const int t = threadIdx.x;
    const int flat = blockIdx.y * 16 + blockIdx.x;
    const int swz = (flat & 7) * 128 + (flat >> 3);  // 1024 blocks, bijective
    const int m0 = (swz >> 4) * 64;
    const int n0 = (swz & 15) * 64;
    const int wid = t >> 6, lane = t & 63;
    const int wm = wid >> 1, wn = wid & 1;
    const int lr = lane & 15, lg = lane >> 4;

    f32x4 acc[2][2] = {};

    auto STAGE = [&](int buf, int kk) {  // 2 gl16 per thread
        const int k0 = kk * 32;
        int idx = wid * 64 + lane;             // 256 slots = 64 rows x 4
        int row = idx >> 2, sl = idx & 3;
        int slx = sl ^ ((row >> 1) & 3);
        gl16(Ag + (size_t)(m0 + row) * D_ + k0 + slx * 8,
             &lA[buf][(wid * 64) * 8]);
        gl16(Bhg + (size_t)(n0 + row) * D_ + k0 + slx * 8,
             &lB[buf][(wid * 64) * 8]);
    };

    STAGE(0, 0);
    STAGE(1, 1);

    for (int kk = 0; kk < 32; ++kk) {
        if (kk < 31) asm volatile("s_waitcnt vmcnt(2)" ::: "memory");
        else         asm volatile("s_waitcnt vmcnt(0)" ::: "memory");
        __builtin_amdgcn_s_barrier();
        if (kk < 30) STAGE((kk + 2) % 3, kk + 2);

        const int cur = kk % 3;
        bf16x8 af[2], bf[2];
#pragma unroll
        for (int m = 0; m < 2; m++) {
            int row = wm * 32 + m * 16 + lr;
            af[m] = *reinterpret_cast<const bf16x8*>(
                &lA[cur][row * 32 + (lg ^ ((row >> 1) & 3)) * 8]);
        }
#pragma unroll
        for (int n = 0; n < 2; n++) {
            int row = wn * 32 + n * 16 + lr;
            bf[n] = *reinterpret_cast<const bf16x8*>(
                &lB[cur][row * 32 + (lg ^ ((row >> 1) & 3)) * 8]);
        }
#pragma unroll
        for (int m = 0; m < 2; m++)
#pragma unroll
            for (int n = 0; n < 2; n++)
                acc[m][n] = mfma16(af[m], bf[n], acc[m][n]);
    }

#pragma unroll
    for (int m = 0; m < 2; m++)
#pragma unroll
        for (int n = 0; n < 2; n++)
#pragma unroll
            for (int r = 0; r < 4; r++) {
                int row = m0 + wm * 32 + m * 16 + lg * 4 + r;
                int col = n0 + wn * 32 + n * 16 + lr;
                out[(size_t)row * D_ + col] = acc[m][n][r] + bias[col];
            }
}

// ---------------------------------------------------------------------------
// Attention (R13): R12 structure + T15-style sub-tile pipeline.
// Per pair: QK^T(s0) -> QK^T(s1) -> SM(s0) -> PV(s0) -> SM(s1) -> PV(s1).
// In-order issue gives same-wave ILP: SM(s0) VALU overlaps QK^T(s1) matrix
// drain; SM(s1) overlaps PV(s0)'s MFMAs. Accumulation order unchanged
// (PV s0 before s1) -> bit-identical results.
// Swapped QK^T (32x32): S^T = mfma32(K_frag, Q_frag); in-register softmax
// via cvt_pk_bf16_f32 + v_permlane32_swap_b32 (T12); no P LDS tile.
// One barrier per tile-PAIR. LDS 64KB, 2 blocks/CU (grid-limited).
// Scores in [0,8]; p = exp2(s*log2e/8 - 4*log2e). Denominator via ones-MFMA
// on the SAME bf16 pa (errors cancel).
// NOTE: SQ_LDS_BANK_CONFLICT ~4.2M == exactly the permlane32_swap count
// (crossbar artifact, ~1/instr) -- not an addressing problem.
// ---------------------------------------------------------------------------
__global__ __launch_bounds__(256, 2)
void attn_kernel(const u16* __restrict__ qa, const u16* __restrict__ ka,
                 const u16* __restrict__ vt, u16* __restrict__ oag) {
    __shared__ __align__(16) u16 Kb[2][2][64 * 64];   // 32 KB
    __shared__ __align__(16) u16 Vb[2][2][64 * 64];   // 32 KB

    const int t = threadIdx.x;
    const int wid = t >> 6, lane = t & 63;
    const int l31 = lane & 31, hi = lane >> 5;
    const int sx = l31 & 7;

    const int flat = blockIdx.y * 16 + blockIdx.x;
    const int swz = (flat & 7) * 64 + (flat >> 3);
    const int bh = swz >> 4;
    const int q0 = (swz & 15) * 128;

    const u16* qbase = qa + (size_t)bh * S_ * HD_;
    const u16* kbase = ka + (size_t)bh * S_ * HD_;
    const u16* vbase = vt + (size_t)bh * HD_ * S_;

    // Q B-frags (col = q = l31, k = d = 16*kc + 8*hi + j)
    bf16x8 qf[4];
#pragma unroll
    for (int kc = 0; kc < 4; kc++)
        qf[kc] = *reinterpret_cast<const bf16x8*>(
            qbase + (size_t)(q0 + wid * 32 + l31) * HD_ + kc * 16 + hi * 8);

    bf16x8 ones;
#pragma unroll
    for (int j = 0; j < 8; j++) ones[j] = (__bf16)1.0f;

    f32x16 oacc0 = {}, oacc1 = {}, ssum = {};

    // stage BOTH tiles of pair starting at k-tile kt2 (linear dest, src-XOR)
    auto STAGE = [&](int buf, int kt2) {
#pragma unroll
        for (int s = 0; s < 2; s++) {
#pragma unroll
            for (int p = 0; p < 2; p++) {
                int slot = p * 256 + wid * 64 + lane;
                int row = slot >> 3, sl = slot & 7;
                int slx = sl ^ (row & 7);
                gl16(kbase + (size_t)((kt2 + s) * 64 + row) * HD_ + slx * 8,
                     &Kb[buf][s][(p * 256 + wid * 64) * 8]);
                gl16(vbase + (size_t)row * S_ + (kt2 + s) * 64 + slx * 8,
                     &Vb[buf][s][(p * 256 + wid * 64) * 8]);
            }
        }
    };

    // swapped QK^T for one sub-tile
    auto QKT = [&](const u16* Kt, f32x16* sacc) {
        __builtin_amdgcn_s_setprio(1);
#pragma unroll
        for (int kc = 0; kc < 4; kc++) {
            int sl = (2 * kc + hi) ^ sx;
            bf16x8 k0 = *reinterpret_cast<const bf16x8*>(&Kt[l31 * 64 + sl * 8]);
            bf16x8 k1 = *reinterpret_cast<const bf16x8*>(&Kt[(32 + l31) * 64 + sl * 8]);
            sacc[0] = mfma32(k0, qf[kc], sacc[0]);
            sacc[1] = mfma32(k1, qf[kc], sacc[1]);
        }
        __builtin_amdgcn_s_setprio(0);
    };

    // softmax + in-register pack to PV A-frags (T12)
    auto SOFTMAX = [&](const f32x16* sacc, bf16x8* pa) {
#pragma unroll
        for (int bb = 0; bb < 2; bb++) {
#pragma unroll
            for (int half = 0; half < 2; half++) {  // sub-block kappa = 2*bb+half
                float pv[8];
#pragma unroll
                for (int r = 0; r < 8; r++) {
                    float tt = __builtin_fmaf(sacc[bb][half * 8 + r],
                                              0.18033688f, -5.7707802f);
                    asm("v_exp_f32 %0, %1" : "=v"(pv[r]) : "v"(tt));
                }
                u32 A1, A2, B1, B2;
                asm("v_cvt_pk_bf16_f32 %0, %1, %2"
                    : "=v"(A1) : "v"(pv[0]), "v"(pv[1]));
                asm("v_cvt_pk_bf16_f32 %0, %1, %2"
                    : "=v"(A2) : "v"(pv[2]), "v"(pv[3]));
                asm("v_cvt_pk_bf16_f32 %0, %1, %2"
                    : "=v"(B1) : "v"(pv[4]), "v"(pv[5]));
                asm("v_cvt_pk_bf16_f32 %0, %1, %2"
                    : "=v"(B2) : "v"(pv[6]), "v"(pv[7]));
                // after swap: A' = {lo:A.lo, hi:B.lo}; B' = {lo:A.hi, hi:B.hi}
                asm("v_permlane32_swap_b32 %0, %1" : "+v"(A1), "+v"(B1));
                asm("v_permlane32_swap_b32 %0, %1" : "+v"(A2), "+v"(B2));
                u32x4 pw;
                pw.x = A1; pw.y = A2; pw.z = B1; pw.w = B2;
                pa[bb * 2 + half] = __builtin_bit_cast(bf16x8, pw);
            }
        }
    };

    // PV + row-sum for one sub-tile
    auto PV = [&](const u16* Vt, const bf16x8* pa) {
        __builtin_amdgcn_s_setprio(1);
#pragma unroll
        for (int k4 = 0; k4 < 4; k4++)
            ssum = mfma32(pa[k4], ones, ssum);
#pragma unroll
        for (int k4 = 0; k4 < 4; k4++) {
            int sl = (2 * k4 + hi) ^ sx;
            bf16x8 v0 = *reinterpret_cast<const bf16x8*>(&Vt[l31 * 64 + sl * 8]);
            bf16x8 v1 = *reinterpret_cast<const bf16x8*>(&Vt[(32 + l31) * 64 + sl * 8]);
            oacc0 = mfma32(pa[k4], v0, oacc0);
            oacc1 = mfma32(pa[k4], v1, oacc1);
        }
        __builtin_amdgcn_s_setprio(0);
    };

    STAGE(0, 0);
    __syncthreads();
    int cur = 0;

    for (int pt = 0; pt < 16; ++pt) {
        if (pt < 15) STAGE(cur ^ 1, (pt + 1) * 2);  // 32KB DMA, hidden under pair

        // T15 pipeline: both QK^Ts up front, then SM/PV staggered
        f32x16 sacc0[2] = {}, sacc1[2] = {};
        QKT(&Kb[cur][0][0], sacc0);
        QKT(&Kb[cur][1][0], sacc1);
        bf16x8 pa0[4], pa1[4];
        SOFTMAX(sacc0, pa0);        // VALU, overlaps QKT(s1) matrix drain
        PV(&Vb[cur][0][0], pa0);    // MFMA
        SOFTMAX(sacc1, pa1);        // VALU, overlaps PV(s0) matrix drain
        PV(&Vb[cur][1][0], pa1);    // MFMA

        __syncthreads();  // drains vmcnt(0): next pair ready; all waves done
        cur ^= 1;
    }

    // epilogue: divide, write bf16 [B,S,D]. O row q=(r&3)+8*(r>>2)+4*hi.
    const int b = bh >> 4, h = bh & 15;
#pragma unroll
    for (int r = 0; r < 16; r++) {
        int q = q0 + wid * 32 + (r & 3) + 8 * (r >> 2) + 4 * hi;
        size_t base = (size_t)(b * S_ + q) * D_ + h * 64;
        float v0 = oacc0[r] / ssum[r];
        float v1 = oacc1[r] / ssum[r];
        oag[base + l31] = f2bf(v0);
        oag[base + 32 + l31] = f2bf(v1);
    }
}

// ---------------------------------------------------------------------------
extern "C" void kernel_launch(void* const* d_in, const int* in_sizes, int n_in,
                              void* d_out, int out_size, void* d_ws, size_t ws_size,
                              hipStream_t stream) {
    (void)in_sizes; (void)n_in; (void)out_size; (void)ws_size;
    const float* x  = (const float*)d_in[0];
    const float* qw = (const float*)d_in[1];
    const float* qb = (const float*)d_in[2];
    const float* kw = (const float*)d_in[3];
    const float* kb = (const float*)d_in[4];
    const float* vw = (const float*)d_in[5];
    const float* vb = (const float*)d_in[6];
    const float* ow = (const float*)d_in[7];
    const float* ob = (const float*)d_in[8];

    u16* ws = (u16*)d_ws;
    const size_t C = 4194304;  // 4096*1024 elements
    u16* xbf = ws + 0 * C;
    u16* wt  = ws + 1 * C;  // 4 transposed bf16 weights [out][in] (q,k,v,o)
    u16* qag = ws + 2 * C;
    u16* kag = ws + 3 * C;
    u16* vtg = ws + 4 * C;
    u16* oag = ws + 5 * C;

    prep_kernel<<<8192, 256, 0, stream>>>(x, qw, kw, vw, ow, xbf, wt);

    // fused QKV projection: A=[4096][1024] x B^T=[3072][1024], LIF epilogue
    qkv_gemm<<<dim3(24, 32), 256, 0, stream>>>(
        xbf, wt, qb, kb, vb, qag, kag, vtg);
    attn_kernel<<<dim3(16, 32), 256, 0, stream>>>(qag, kag, vtg, oag);
    // o-projection: plain bf16, tile 64x64 -> 1024 blocks = 4/CU
    o_gemm<<<dim3(16, 64), 256, 0, stream>>>(
        oag, wt + 3 * 1048576, ob, (float*)d_out);
}

// Round 14
// 107.027 us; speedup vs baseline: 1.0333x; 1.0333x over previous
//
#include <hip/hip_runtime.h>
#include <hip/hip_bf16.h>
#include <stdint.h>

typedef unsigned short u16;
typedef unsigned int u32;
typedef __bf16 bf16x8 __attribute__((ext_vector_type(8)));
typedef float f32x4 __attribute__((ext_vector_type(4)));
typedef float f32x16 __attribute__((ext_vector_type(16)));
typedef u32 u32x4 __attribute__((ext_vector_type(4)));

#define B_   2
#define S_   2048
#define D_   1024
#define H_   16
#define HD_  64

__device__ __forceinline__ u16 f2bf(float f) {
    u32 u = __float_as_uint(f);
    u32 r = (u + 0x7FFFu + ((u >> 16) & 1u)) >> 16;   // RNE; inputs never NaN/Inf
    return (u16)r;
}
__device__ __forceinline__ float bf2f(u16 s) { return __uint_as_float(((u32)s) << 16); }

__device__ __forceinline__ f32x4 mfma16(bf16x8 a, bf16x8 b, f32x4 c) {
    return __builtin_amdgcn_mfma_f32_16x16x32_bf16(a, b, c, 0, 0, 0);
}
__device__ __forceinline__ f32x16 mfma32(bf16x8 a, bf16x8 b, f32x16 c) {
    return __builtin_amdgcn_mfma_f32_32x32x16_bf16(a, b, c, 0, 0, 0);
}

// async global->LDS, 16B per lane; lds dest must be wave-uniform base (+lane*16)
__device__ __forceinline__ void gl16(const u16* g, u16* l) {
    __builtin_amdgcn_global_load_lds(
        (const __attribute__((address_space(1))) void*)g,
        (__attribute__((address_space(3))) void*)l, 16, 0, 0);
}

// ---------------------------------------------------------------------------
// Fused prep: blocks 0..4095 convert x fp32->bf16 (float4/thread);
// blocks 4096..8191 transpose+convert the 4 weights (z = q/k/v/o).
// ---------------------------------------------------------------------------
__global__ void prep_kernel(const float* __restrict__ x,
                            const float* __restrict__ qw, const float* __restrict__ kw,
                            const float* __restrict__ vw, const float* __restrict__ ow,
                            u16* __restrict__ xbf, u16* __restrict__ wt_all) {
    __shared__ float tile[32][33];
    const int bid = blockIdx.x;
    const int t = threadIdx.x;
    if (bid < 4096) {
        int i = bid * 256 + t;
        float4 v = reinterpret_cast<const float4*>(x)[i];
        uint2 hp;
        hp.x = (u32)f2bf(v.x) | ((u32)f2bf(v.y) << 16);
        hp.y = (u32)f2bf(v.z) | ((u32)f2bf(v.w) << 16);
        reinterpret_cast<uint2*>(xbf)[i] = hp;
        return;
    }
    const int f = bid - 4096;
    const int z = f >> 10;           // weight select
    const int bi = (f & 1023) >> 5;  // input-dim block
    const int bj = f & 31;           // output-dim block
    const float* w = (z == 0) ? qw : (z == 1) ? kw : (z == 2) ? vw : ow;
    u16* thi = wt_all + (size_t)z * 1048576;
    const int tx = t & 31, ty = t >> 5;  // 32 x 8
#pragma unroll
    for (int k = 0; k < 4; k++) {
        int r = ty + k * 8;
        tile[r][tx] = w[(size_t)(bi * 32 + r) * D_ + bj * 32 + tx];
    }
    __syncthreads();
#pragma unroll
    for (int k = 0; k < 4; k++) {
        int r = ty + k * 8;
        thi[(size_t)(bj * 32 + r) * D_ + bi * 32 + tx] = f2bf(tile[tx][r]);
    }
}

// ---------------------------------------------------------------------------
// Fused QKV projection GEMM, plain bf16, LIF epilogue. T4 pipeline:
// 3 LDS buffers, per k-step: counted vmcnt(4) -> raw s_barrier (no drain)
// -> STAGE(k+2) -> compute(k). Tile 128x128, BK=32, 48KB LDS -> 3 blocks/CU.
// proj 0/1 (q/k) -> [bh][s][d]; proj 2 (v) -> [bh][d][s], 8B packed stores.
// ---------------------------------------------------------------------------
__global__ __launch_bounds__(256, 3)
void qkv_gemm(const u16* __restrict__ Ag, const u16* __restrict__ Bg,
              const float* __restrict__ qb, const float* __restrict__ kb,
              const float* __restrict__ vb,
              u16* __restrict__ o0, u16* __restrict__ o1, u16* __restrict__ o2) {
    __shared__ __align__(16) u16 lA[3][128 * 32];  // 24 KB
    __shared__ __align__(16) u16 lB[3][128 * 32];  // 24 KB

    const int t = threadIdx.x;
    const int flat = blockIdx.y * 24 + blockIdx.x;
    const int swz = (flat & 7) * 96 + (flat >> 3);   // bijective, 8 XCD chunks
    const int m0 = (swz / 24) * 128;
    const int n0 = (swz % 24) * 128;
    const int wid = t >> 6, lane = t & 63;
    const int wm = wid >> 1, wn = wid & 1;
    const int lr = lane & 15, lg = lane >> 4;

    f32x4 acc[4][4] = {};

    auto STAGE = [&](int buf, int kk) {  // 4 gl16 per thread
        const int k0 = kk * 32;
#pragma unroll
        for (int p = 0; p < 2; p++) {
            int idx = p * 256 + wid * 64 + lane;
            int row = idx >> 2, sl = idx & 3;
            int slx = sl ^ ((row >> 1) & 3);
            gl16(Ag + (size_t)(m0 + row) * D_ + k0 + slx * 8,
                 &lA[buf][(p * 256 + wid * 64) * 8]);
            gl16(Bg + (size_t)(n0 + row) * D_ + k0 + slx * 8,
                 &lB[buf][(p * 256 + wid * 64) * 8]);
        }
    };

    STAGE(0, 0);
    STAGE(1, 1);

    for (int kk = 0; kk < 32; ++kk) {
        if (kk < 31) asm volatile("s_waitcnt vmcnt(4)" ::: "memory");
        else         asm volatile("s_waitcnt vmcnt(0)" ::: "memory");
        __builtin_amdgcn_s_barrier();
        if (kk < 30) STAGE((kk + 2) % 3, kk + 2);  // lands over next 2 k-steps

        const int cur = kk % 3;
        bf16x8 af[4], bf[4];
#pragma unroll
        for (int m = 0; m < 4; m++) {
            int row = wm * 64 + m * 16 + lr;
            af[m] = *reinterpret_cast<const bf16x8*>(
                &lA[cur][row * 32 + (lg ^ ((row >> 1) & 3)) * 8]);
        }
#pragma unroll
        for (int n = 0; n < 4; n++) {
            int row = wn * 64 + n * 16 + lr;
            bf[n] = *reinterpret_cast<const bf16x8*>(
                &lB[cur][row * 32 + (lg ^ ((row >> 1) & 3)) * 8]);
        }
#pragma unroll
        for (int m = 0; m < 4; m++)
#pragma unroll
            for (int n = 0; n < 4; n++)
                acc[m][n] = mfma16(af[m], bf[n], acc[m][n]);
    }

    // ---- epilogue: bias + LIF + scatter ----
    const int col0f = n0 + wn * 64;
    const int proj = col0f >> 10;  // whole wave-tile shares one proj (64 | 1024)
    const float* bp = (proj == 0) ? qb : (proj == 1) ? kb : vb;
    u16* dst = (proj == 0) ? o0 : (proj == 1) ? o1 : o2;
#pragma unroll
    for (int m = 0; m < 4; m++) {
#pragma unroll
        for (int n = 0; n < 4; n++) {
            u16 agg4[4];
#pragma unroll
            for (int r = 0; r < 4; r++) {
                int row = m0 + wm * 64 + m * 16 + lg * 4 + r;
                int colp = (col0f + n * 16 + lr) & 1023;
                float cur_i = acc[m][n][r] + bp[colp];
                // LIF: 4 steps, subtract reset (detached), spike after update
                float mem = 0.f;
                int cnt = 0;
#pragma unroll
                for (int tt = 0; tt < 4; tt++) {
                    float reset = (mem > 1.f) ? 1.f : 0.f;
                    mem = 0.95f * mem;
                    mem = mem + cur_i;
                    mem = mem - reset;
                    cnt += (mem > 1.f) ? 1 : 0;
                }
                // cnt*0.25 is exactly representable in bf16: truncate, no RNE
                u16 agg = (u16)(__float_as_uint((float)cnt * 0.25f) >> 16);
                if (proj != 2) {
                    int b = row >> 11, s = row & 2047;
                    int h = colp >> 6, d = colp & 63;
                    dst[((size_t)(b * H_ + h) * S_ + s) * HD_ + d] = agg;
                } else {
                    agg4[r] = agg;
                }
            }
            if (proj == 2) {
                // [bh][d][s]: 4 consecutive s per thread -> one 8B store
                int row0 = m0 + wm * 64 + m * 16 + lg * 4;
                int colp = (col0f + n * 16 + lr) & 1023;
                int b = row0 >> 11, s = row0 & 2047;
                int h = colp >> 6, d = colp & 63;
                uint2 pk;
                pk.x = (u32)agg4[0] | ((u32)agg4[1] << 16);
                pk.y = (u32)agg4[2] | ((u32)agg4[3] << 16);
                *reinterpret_cast<uint2*>(
                    &dst[((size_t)(b * H_ + h) * HD_ + d) * S_ + s]) = pk;
            }
        }
    }
}

// ---------------------------------------------------------------------------
// Output projection, plain bf16, T4 pipeline (3 buffers, counted vmcnt(2)).
// C = a @ W^T + bias, fp32 out. Tile 64x64, BK=32. 24KB LDS -> 4 blocks/CU.
// ---------------------------------------------------------------------------
__global__ __launch_bounds__(256, 4)
void o_gemm(const u16* __restrict__ Ag, const u16* __restrict__ Bhg,
            const float* __restrict__ bias, float* __restrict__ out) {
    __shared__ __align__(16) u16 lA[3][64 * 32];    // 12 KB
    __shared__ __align__(16) u16 lB[3][64 * 32];    // 12 KB

    const int t = threadIdx.x;
    const int flat = blockIdx.y * 16 + blockIdx.x;
    const int swz = (flat & 7) * 128 + (flat >> 3);  // 1024 blocks, bijective
    const int m0 = (swz >> 4) * 64;
    const int n0 = (swz & 15) * 64;
    const int wid = t >> 6, lane = t & 63;
    const int wm = wid >> 1, wn = wid & 1;
    const int lr = lane & 15, lg = lane >> 4;

    f32x4 acc[2][2] = {};

    auto STAGE = [&](int buf, int kk) {  // 2 gl16 per thread
        const int k0 = kk * 32;
        int idx = wid * 64 + lane;             // 256 slots = 64 rows x 4
        int row = idx >> 2, sl = idx & 3;
        int slx = sl ^ ((row >> 1) & 3);
        gl16(Ag + (size_t)(m0 + row) * D_ + k0 + slx * 8,
             &lA[buf][(wid * 64) * 8]);
        gl16(Bhg + (size_t)(n0 + row) * D_ + k0 + slx * 8,
             &lB[buf][(wid * 64) * 8]);
    };

    STAGE(0, 0);
    STAGE(1, 1);

    for (int kk = 0; kk < 32; ++kk) {
        if (kk < 31) asm volatile("s_waitcnt vmcnt(2)" ::: "memory");
        else         asm volatile("s_waitcnt vmcnt(0)" ::: "memory");
        __builtin_amdgcn_s_barrier();
        if (kk < 30) STAGE((kk + 2) % 3, kk + 2);

        const int cur = kk % 3;
        bf16x8 af[2], bf[2];
#pragma unroll
        for (int m = 0; m < 2; m++) {
            int row = wm * 32 + m * 16 + lr;
            af[m] = *reinterpret_cast<const bf16x8*>(
                &lA[cur][row * 32 + (lg ^ ((row >> 1) & 3)) * 8]);
        }
#pragma unroll
        for (int n = 0; n < 2; n++) {
            int row = wn * 32 + n * 16 + lr;
            bf[n] = *reinterpret_cast<const bf16x8*>(
                &lB[cur][row * 32 + (lg ^ ((row >> 1) & 3)) * 8]);
        }
#pragma unroll
        for (int m = 0; m < 2; m++)
#pragma unroll
            for (int n = 0; n < 2; n++)
                acc[m][n] = mfma16(af[m], bf[n], acc[m][n]);
    }

#pragma unroll
    for (int m = 0; m < 2; m++)
#pragma unroll
        for (int n = 0; n < 2; n++)
#pragma unroll
            for (int r = 0; r < 4; r++) {
                int row = m0 + wm * 32 + m * 16 + lg * 4 + r;
                int col = n0 + wn * 32 + n * 16 + lr;
                out[(size_t)row * D_ + col] = acc[m][n][r] + bias[col];
            }
}

// ---------------------------------------------------------------------------
// Attention (R14): 512-thread blocks (8 waves x 32 q = 256 q rows/block) --
// halves staging DMA per q (L2->LDS was ~23 TB/s = 66% of L2 ceiling at R12)
// -- plus pair-granularity T4: 3 pair-buffers (96 KB), counted vmcnt(4),
// raw s_barrier; pair DMA lands across TWO pair-compute regions, no drain
// until tail. Compute body = R12 verbatim (T15 stagger reverted, m253).
// Swapped QK^T (32x32): S^T = mfma32(K_frag, Q_frag); in-register softmax
// via cvt_pk_bf16_f32 + v_permlane32_swap_b32 (T12); no P LDS tile.
// Grid (8 q-tiles of 256, 32 bh) = 256 blocks = 1 block/CU, 2 waves/SIMD.
// Scores in [0,8]; p = exp2(s*log2e/8 - 4*log2e). Denominator via ones-MFMA
// on the SAME bf16 pa (errors cancel).
// NOTE: SQ_LDS_BANK_CONFLICT ~4.2M == permlane32_swap count (crossbar
// artifact, ~1/instr) -- not an addressing problem.
// ---------------------------------------------------------------------------
__global__ __launch_bounds__(512, 1)
void attn_kernel(const u16* __restrict__ qa, const u16* __restrict__ ka,
                 const u16* __restrict__ vt, u16* __restrict__ oag) {
    __shared__ __align__(16) u16 Kb[3][2][64 * 64];   // 48 KB
    __shared__ __align__(16) u16 Vb[3][2][64 * 64];   // 48 KB

    const int t = threadIdx.x;
    const int wid = t >> 6, lane = t & 63;
    const int l31 = lane & 31, hi = lane >> 5;
    const int sx = l31 & 7;

    // grid 8x32 = 256 blocks; XCD chunks of 32 swz = 4 whole bh
    const int flat = blockIdx.y * 8 + blockIdx.x;
    const int swz = (flat & 7) * 32 + (flat >> 3);
    const int bh = swz >> 3;
    const int q0 = (swz & 7) * 256;

    const u16* qbase = qa + (size_t)bh * S_ * HD_;
    const u16* kbase = ka + (size_t)bh * S_ * HD_;
    const u16* vbase = vt + (size_t)bh * HD_ * S_;

    // Q B-frags (col = q = l31, k = d = 16*kc + 8*hi + j)
    bf16x8 qf[4];
#pragma unroll
    for (int kc = 0; kc < 4; kc++)
        qf[kc] = *reinterpret_cast<const bf16x8*>(
            qbase + (size_t)(q0 + wid * 32 + l31) * HD_ + kc * 16 + hi * 8);

    bf16x8 ones;
#pragma unroll
    for (int j = 0; j < 8; j++) ones[j] = (__bf16)1.0f;

    f32x16 oacc0 = {}, oacc1 = {}, ssum = {};

    // stage BOTH tiles of pair starting at k-tile 2*pt: 4 gl16/thread
    // (512 threads x 16B = 8KB = one full 64x64 K or V tile per pass)
    auto STAGE = [&](int buf, int kt2) {
        const int row = t >> 3, sl = t & 7;
        const int slx = sl ^ (row & 7);
        const int lbase = (wid * 64) * 8;
#pragma unroll
        for (int s = 0; s < 2; s++) {
            gl16(kbase + (size_t)((kt2 + s) * 64 + row) * HD_ + slx * 8,
                 &Kb[buf][s][lbase]);
            gl16(vbase + (size_t)row * S_ + (kt2 + s) * 64 + slx * 8,
                 &Vb[buf][s][lbase]);
        }
    };

    // one k-tile: swapped QK^T -> in-register softmax (T12) -> PV (R12 body)
    auto COMPUTE = [&](const u16* Kt, const u16* Vt) {
        f32x16 sacc[2] = {};
        __builtin_amdgcn_s_setprio(1);
#pragma unroll
        for (int kc = 0; kc < 4; kc++) {
            int sl = (2 * kc + hi) ^ sx;
            bf16x8 k0 = *reinterpret_cast<const bf16x8*>(&Kt[l31 * 64 + sl * 8]);
            bf16x8 k1 = *reinterpret_cast<const bf16x8*>(&Kt[(32 + l31) * 64 + sl * 8]);
            sacc[0] = mfma32(k0, qf[kc], sacc[0]);
            sacc[1] = mfma32(k1, qf[kc], sacc[1]);
        }
        __builtin_amdgcn_s_setprio(0);
        bf16x8 pa[4];
#pragma unroll
        for (int bb = 0; bb < 2; bb++) {
#pragma unroll
            for (int half = 0; half < 2; half++) {  // sub-block kappa = 2*bb+half
                float pv[8];
#pragma unroll
                for (int r = 0; r < 8; r++) {
                    float tt = __builtin_fmaf(sacc[bb][half * 8 + r],
                                              0.18033688f, -5.7707802f);
                    asm("v_exp_f32 %0, %1" : "=v"(pv[r]) : "v"(tt));
                }
                u32 A1, A2, B1, B2;
                asm("v_cvt_pk_bf16_f32 %0, %1, %2"
                    : "=v"(A1) : "v"(pv[0]), "v"(pv[1]));
                asm("v_cvt_pk_bf16_f32 %0, %1, %2"
                    : "=v"(A2) : "v"(pv[2]), "v"(pv[3]));
                asm("v_cvt_pk_bf16_f32 %0, %1, %2"
                    : "=v"(B1) : "v"(pv[4]), "v"(pv[5]));
                asm("v_cvt_pk_bf16_f32 %0, %1, %2"
                    : "=v"(B2) : "v"(pv[6]), "v"(pv[7]));
                // after swap: A' = {lo:A.lo, hi:B.lo}; B' = {lo:A.hi, hi:B.hi}
                asm("v_permlane32_swap_b32 %0, %1" : "+v"(A1), "+v"(B1));
                asm("v_permlane32_swap_b32 %0, %1" : "+v"(A2), "+v"(B2));
                u32x4 pw;
                pw.x = A1; pw.y = A2; pw.z = B1; pw.w = B2;
                pa[bb * 2 + half] = __builtin_bit_cast(bf16x8, pw);
            }
        }
        __builtin_amdgcn_s_setprio(1);
#pragma unroll
        for (int k4 = 0; k4 < 4; k4++)
            ssum = mfma32(pa[k4], ones, ssum);
#pragma unroll
        for (int k4 = 0; k4 < 4; k4++) {
            int sl = (2 * k4 + hi) ^ sx;
            bf16x8 v0 = *reinterpret_cast<const bf16x8*>(&Vt[l31 * 64 + sl * 8]);
            bf16x8 v1 = *reinterpret_cast<const bf16x8*>(&Vt[(32 + l31) * 64 + sl * 8]);
            oacc0 = mfma32(pa[k4], v0, oacc0);
            oacc1 = mfma32(pa[k4], v1, oacc1);
        }
        __builtin_amdgcn_s_setprio(0);
    };

    STAGE(0, 0);   // pair 0: 4 gl16/thread
    STAGE(1, 2);   // pair 1: 4 gl16/thread

    for (int pt = 0; pt < 16; ++pt) {
        // counted wait: pair pt landed; pair pt+1 (4 ops) stays in flight
        if (pt < 15) asm volatile("s_waitcnt vmcnt(4)" ::: "memory");
        else         asm volatile("s_waitcnt vmcnt(0)" ::: "memory");
        __builtin_amdgcn_s_barrier();
        if (pt < 14) STAGE((pt + 2) % 3, (pt + 2) * 2);  // lands over 2 pairs

        const int cur = pt % 3;
        COMPUTE(&Kb[cur][0][0], &Vb[cur][0][0]);
        COMPUTE(&Kb[cur][1][0], &Vb[cur][1][0]);
    }

    // epilogue: divide, write bf16 [B,S,D]. O row q=(r&3)+8*(r>>2)+4*hi.
    const int b = bh >> 4, h = bh & 15;
#pragma unroll
    for (int r = 0; r < 16; r++) {
        int q = q0 + wid * 32 + (r & 3) + 8 * (r >> 2) + 4 * hi;
        size_t base = (size_t)(b * S_ + q) * D_ + h * 64;
        float v0 = oacc0[r] / ssum[r];
        float v1 = oacc1[r] / ssum[r];
        oag[base + l31] = f2bf(v0);
        oag[base + 32 + l31] = f2bf(v1);
    }
}

// ---------------------------------------------------------------------------
extern "C" void kernel_launch(void* const* d_in, const int* in_sizes, int n_in,
                              void* d_out, int out_size, void* d_ws, size_t ws_size,
                              hipStream_t stream) {
    (void)in_sizes; (void)n_in; (void)out_size; (void)ws_size;
    const float* x  = (const float*)d_in[0];
    const float* qw = (const float*)d_in[1];
    const float* qb = (const float*)d_in[2];
    const float* kw = (const float*)d_in[3];
    const float* kb = (const float*)d_in[4];
    const float* vw = (const float*)d_in[5];
    const float* vb = (const float*)d_in[6];
    const float* ow = (const float*)d_in[7];
    const float* ob = (const float*)d_in[8];

    u16* ws = (u16*)d_ws;
    const size_t C = 4194304;  // 4096*1024 elements
    u16* xbf = ws + 0 * C;
    u16* wt  = ws + 1 * C;  // 4 transposed bf16 weights [out][in] (q,k,v,o)
    u16* qag = ws + 2 * C;
    u16* kag = ws + 3 * C;
    u16* vtg = ws + 4 * C;
    u16* oag = ws + 5 * C;

    prep_kernel<<<8192, 256, 0, stream>>>(x, qw, kw, vw, ow, xbf, wt);

    // fused QKV projection: A=[4096][1024] x B^T=[3072][1024], LIF epilogue
    qkv_gemm<<<dim3(24, 32), 256, 0, stream>>>(
        xbf, wt, qb, kb, vb, qag, kag, vtg);
    attn_kernel<<<dim3(8, 32), 512, 0, stream>>>(qag, kag, vtg, oag);
    // o-projection: plain bf16, tile 64x64 -> 1024 blocks = 4/CU
    o_gemm<<<dim3(16, 64), 256, 0, stream>>>(
        oag, wt + 3 * 1048576, ob, (float*)d_out);
}